// Round 6
// baseline (123.826 us; speedup 1.0000x reference)
//
#include <hip/hip_runtime.h>

typedef float v2f __attribute__((ext_vector_type(2)));

#define W_IMG 512
#define H_IMG 512
#define PLANES 96                  // 32 * 3
#define NPIX 25165824.0            // 96 * 512 * 512

#define SW 64                      // output cols per wave
#define SH 64                      // output rows per wave
#define NROWS (SH + 10)            // 74 streamed input rows
#define WPB 4                      // waves per block
#define XS (W_IMG / SW)            // 8
#define YB (H_IMG / SH)            // 8
#define BLOCKS_PER_PLANE (XS * YB / WPB)   // 16

__global__ void ssim_zero(double* acc) {
    if (threadIdx.x == 0) acc[0] = 0.0;
}

__global__ void ssim_final(const double* __restrict__ acc, float* __restrict__ out) {
    if (threadIdx.x == 0) out[0] = (float)(1.0 - acc[0] / NPIX);
}

// unaligned (4B-aligned) 16B global load
__device__ __forceinline__ float4 ld4u(const float* p) {
    float4 v;
    __builtin_memcpy(&v, p, 16);
    return v;
}

// packed fp32 ops (VOP3P). All-VGPR operands: safe encoding.
__device__ __forceinline__ v2f pk_mul(v2f a, v2f b) {
    v2f d; asm("v_pk_mul_f32 %0, %1, %2" : "=v"(d) : "v"(a), "v"(b)); return d;
}
__device__ __forceinline__ v2f pk_add(v2f a, v2f b) {
    v2f d; asm("v_pk_add_f32 %0, %1, %2" : "=v"(d) : "v"(a), "v"(b)); return d;
}
__device__ __forceinline__ v2f pk_fma(v2f a, v2f b, v2f c) {
    v2f d; asm("v_pk_fma_f32 %0, %1, %2, %3" : "=v"(d) : "v"(a), "v"(b), "v"(c)); return d;
}

__global__ __launch_bounds__(256, 2)
void ssim_main(const float* __restrict__ img1,
               const float* __restrict__ img2,
               double* __restrict__ acc)
{
    // normalized 11-tap Gaussian, sigma=1.5 (matches reference _create_window)
    constexpr float G[11] = {
        0.00102838f, 0.00759875f, 0.03600077f, 0.10936070f, 0.21300540f,
        0.26601180f,
        0.21300540f, 0.10936070f, 0.03600077f, 0.00759875f, 0.00102838f };
    constexpr float K_C1 = 0.0001f;
    constexpr float K_C2 = 0.0009f;

    __shared__ float wred[WPB];

    const int tid = threadIdx.x;
    const int wv  = tid >> 6;
    const int L   = tid & 63;
    const int wid = blockIdx.x * WPB + wv;   // 0..63 per plane
    const int c0  = (wid & (XS - 1)) * SW;
    const int r0  = (wid >> 3) * SH;
    const size_t pofs = (size_t)blockIdx.y * (H_IMG * W_IMG);
    const float* __restrict__ p1 = img1 + pofs;
    const float* __restrict__ p2 = img2 + pofs;

    const int c  = c0 + L;       // this lane's output column
    const int ws = c - 5;        // window start col (may be out of range)

    // 3 clamped float4 load bases per image (cols), computed once
    int bofs[3];
    #pragma unroll
    for (int i = 0; i < 3; ++i) {
        int bb = ws + 4 * i;
        bb = bb < 0 ? 0 : bb;
        bb = bb > (W_IMG - 4) ? (W_IMG - 4) : bb;
        bofs[i] = bb;
    }

    // per-lane 12-slot coefficient vector mapped to the CLAMPED load slots:
    // slot (i,j) holds G[tap] iff its loaded col is the window's tap (0..10),
    // in-bounds, and not already covered by an earlier (overlapping) group.
    float Cs[12];
    {
        int prev_end = -1;
        #pragma unroll
        for (int i = 0; i < 3; ++i) {
            #pragma unroll
            for (int jj = 0; jj < 4; ++jj) {
                const int col = bofs[i] + jj;
                const int tap = col - ws;
                float g = 0.f;
                #pragma unroll
                for (int t = 0; t < 11; ++t) g = (tap == t) ? G[t] : g;
                Cs[4 * i + jj] = (col > prev_end) ? g : 0.f;
            }
            prev_end = bofs[i] + 3;
        }
    }
    v2f C2[6];
    #pragma unroll
    for (int p = 0; p < 6; ++p) { C2[p].x = Cs[2 * p]; C2[p].y = Cs[2 * p + 1]; }

    // rings: channel-paired for packed V-conv. (m1,m2), (h11,h22), h12
    v2f  ringA[11], ringB[11];
    float ringC[11];
    float lsum = 0.f;

    #pragma unroll 1
    for (int sb = 0; sb < 77; sb += 11) {
        #pragma unroll
        for (int j = 0; j < 11; ++j) {
            const int s  = sb + j;          // streamed row; ring slot = s%11 = j
            const int gr = r0 - 5 + s;
            const bool rv = (s < NROWS) && ((unsigned)gr < (unsigned)H_IMG);

            // ---- phase 1: issue this row's 6 global loads ----
            float4 la0, la1, la2, lb0, lb1, lb2;
            if (rv) {
                const float* q1 = p1 + gr * W_IMG;
                const float* q2 = p2 + gr * W_IMG;
                la0 = ld4u(q1 + bofs[0]);
                la1 = ld4u(q1 + bofs[1]);
                la2 = ld4u(q1 + bofs[2]);
                lb0 = ld4u(q2 + bofs[0]);
                lb1 = ld4u(q2 + bofs[1]);
                lb2 = ld4u(q2 + bofs[2]);
            }

            // ---- phase 2: V-conv + SSIM for output row s-11 (ring-only) ----
            if (s >= 11 && s < SH + 11) {
                v2f MA, MB;
                MA.x = 0.f; MA.y = 0.f; MB.x = 0.f; MB.y = 0.f;
                float e12 = 0.f;
                #pragma unroll
                for (int k = 0; k < 11; ++k) {
                    const int sl = (j + k) % 11;   // compile-time
                    v2f gg; gg.x = G[k]; gg.y = G[k];
                    MA = pk_fma(gg, ringA[sl], MA);
                    MB = pk_fma(gg, ringB[sl], MB);
                    e12 = fmaf(G[k], ringC[sl], e12);
                }
                const float M1 = MA.x, M2 = MA.y, E11 = MB.x, E22 = MB.y;
                const float mu1s = M1 * M1, mu2s = M2 * M2, mu12 = M1 * M2;
                const float v11 = fmaxf(E11 - mu1s, 0.f);
                const float v22 = fmaxf(E22 - mu2s, 0.f);
                const float v12 = e12 - mu12;
                const float num = fmaf(2.f, mu12, K_C1) * fmaf(2.f, v12, K_C2);
                const float den = (mu1s + mu2s + K_C1) * (v11 + v22 + K_C2);
                lsum = fmaf(num, __builtin_amdgcn_rcpf(den), lsum);
            }

            // ---- phase 3: packed H-conv on row s -> push ring slot j ----
            if (s < NROWS) {
                if (rv) {
                    v2f A[6], B[6];
                    A[0].x = la0.x; A[0].y = la0.y;  A[1].x = la0.z; A[1].y = la0.w;
                    A[2].x = la1.x; A[2].y = la1.y;  A[3].x = la1.z; A[3].y = la1.w;
                    A[4].x = la2.x; A[4].y = la2.y;  A[5].x = la2.z; A[5].y = la2.w;
                    B[0].x = lb0.x; B[0].y = lb0.y;  B[1].x = lb0.z; B[1].y = lb0.w;
                    B[2].x = lb1.x; B[2].y = lb1.y;  B[3].x = lb1.z; B[3].y = lb1.w;
                    B[4].x = lb2.x; B[4].y = lb2.y;  B[5].x = lb2.z; B[5].y = lb2.w;

                    v2f m1v, m2v, h11v, h22v, h12v;
                    m1v.x = 0.f; m1v.y = 0.f; m2v = m1v;
                    h11v = m1v; h22v = m1v; h12v = m1v;
                    #pragma unroll
                    for (int p = 0; p < 6; ++p) {
                        const v2f t1 = pk_mul(C2[p], A[p]);
                        const v2f t2 = pk_mul(C2[p], B[p]);
                        m1v  = pk_add(m1v, t1);
                        m2v  = pk_add(m2v, t2);
                        h11v = pk_fma(t1, A[p], h11v);
                        h22v = pk_fma(t2, B[p], h22v);
                        h12v = pk_fma(t1, B[p], h12v);
                    }
                    ringA[j].x = m1v.x + m1v.y;   ringA[j].y = m2v.x + m2v.y;
                    ringB[j].x = h11v.x + h11v.y; ringB[j].y = h22v.x + h22v.y;
                    ringC[j]   = h12v.x + h12v.y;
                } else {
                    ringA[j].x = 0.f; ringA[j].y = 0.f;
                    ringB[j].x = 0.f; ringB[j].y = 0.f;
                    ringC[j]   = 0.f;
                }
            }
        }
    }

    // ---- wave reduce -> one barrier -> one atomic per block ----
    #pragma unroll
    for (int off = 32; off > 0; off >>= 1)
        lsum += __shfl_down(lsum, off, 64);
    if (L == 0) wred[wv] = lsum;
    __syncthreads();
    if (tid == 0)
        atomicAdd(acc, (double)(wred[0] + wred[1] + wred[2] + wred[3]));
}

extern "C" void kernel_launch(void* const* d_in, const int* in_sizes, int n_in,
                              void* d_out, int out_size, void* d_ws, size_t ws_size,
                              hipStream_t stream) {
    const float* img1 = (const float*)d_in[0];
    const float* img2 = (const float*)d_in[1];
    float* out  = (float*)d_out;
    double* acc = (double*)d_ws;

    ssim_zero<<<dim3(1), dim3(64), 0, stream>>>(acc);
    ssim_main<<<dim3(BLOCKS_PER_PLANE, PLANES), dim3(256), 0, stream>>>(img1, img2, acc);
    ssim_final<<<dim3(1), dim3(64), 0, stream>>>(acc, out);
}